// Round 4
// baseline (543.787 us; speedup 1.0000x reference)
//
#include <hip/hip_runtime.h>
#include <stdint.h>

#define DEVI __device__ __forceinline__

typedef short bf16x8 __attribute__((ext_vector_type(8)));
typedef float f32x4 __attribute__((ext_vector_type(4)));

DEVI float b2f(unsigned short u) {
  union { unsigned u32; float f; } x;
  x.u32 = ((unsigned)u) << 16;
  return x.f;
}
DEVI unsigned short f2b(float f) {
  union { float f32; unsigned u32; } x;
  x.f32 = f;
  unsigned u = x.u32;
  return (unsigned short)((u + 0x7FFFu + ((u >> 16) & 1u)) >> 16);
}
DEVI unsigned short to_b(float v) { return f2b(v); }
DEVI unsigned short to_b(unsigned short v) { return v; }

// ------------------------------------------------------------ convert f32->bf16
__global__ void k_cvt(const float* __restrict__ src, unsigned short* __restrict__ dst, int n) {
  int i = blockIdx.x * 256 + threadIdx.x;
  if (i < n) dst[i] = f2b(src[i]);
}

// ---------------------------------------------------------------- transpose
// dst[c][r] = bf16(src[r][c]); src is f32 or bf16.
template <typename T>
__global__ void k_transpose(const T* __restrict__ src, int src_ld,
                            unsigned short* __restrict__ dst, int dst_ld,
                            int rows, int cols) {
  __shared__ unsigned short t[32][33];
  int tx = threadIdx.x & 31, ty = threadIdx.x >> 5;
  int r0 = blockIdx.y * 32, c0 = blockIdx.x * 32;
#pragma unroll
  for (int i = 0; i < 4; i++) {
    int r = r0 + ty + i * 8, cc = c0 + tx;
    if (r < rows && cc < cols) t[ty + i * 8][tx] = to_b(src[(size_t)r * src_ld + cc]);
  }
  __syncthreads();
#pragma unroll
  for (int i = 0; i < 4; i++) {
    int dr = c0 + ty + i * 8, dc = r0 + tx;
    if (dr < cols && dc < rows) dst[(size_t)dr * dst_ld + dc] = t[tx][ty + i * 8];
  }
}

// ------------------------------------------------------- positional features
DEVI float gamma_prob(float ap, int i) {
  float mean = 48.f * (float)(i + 1);
  float conc = (mean / 24.f) * (mean / 24.f);
  float rate = mean / 576.f;
  if (ap == 0.f) return 1e-8f;
  float logp = (conc - 1.f) * logf(ap) - rate * ap - (lgammaf(conc) - conc * logf(rate));
  return expf(logp) + 1e-8f;
}

__global__ void k_posmax(float* pmax) {
  int idx = blockIdx.x * 256 + threadIdx.x;  // 3071*32 entries
  float prob = 0.f;
  if (idx < 3071 * 32) {
    int m = idx >> 5, i = idx & 31;
    float ap = fabsf((float)(m - 1535));
    prob = gamma_prob(ap, i);
  }
#pragma unroll
  for (int s = 1; s < 64; s <<= 1) prob = fmaxf(prob, __shfl_xor(prob, s, 64));
  if ((threadIdx.x & 63) == 0) atomicMax((unsigned int*)pmax, __float_as_uint(prob));
}

__global__ void k_emb(unsigned short* __restrict__ emb, const float* __restrict__ pmax) {
  int idx = blockIdx.x * 256 + threadIdx.x;  // 3071*96
  if (idx >= 3071 * 96) return;
  int m = idx / 96, cc = idx % 96;
  float ap = fabsf((float)(m - 1535));
  float val;
  if (cc < 32) {
    float max_range = logf(1536.f) * 1.4426950408889634f;
    float l = 3.f + (float)cc * (max_range - 3.f) / 31.f;
    val = exp2f(-ap * exp2f(-l));
  } else if (cc < 64) {
    int i = cc - 32;
    float width = exp2f((float)(i + 1)) - 1.f;
    val = (width > ap) ? 1.f : 0.f;
  } else {
    val = gamma_prob(ap, cc - 64) / pmax[0];
  }
  float sgn = (m > 1535) ? 1.f : ((m < 1535) ? -1.f : 0.f);
  emb[(size_t)m * 192 + cc] = f2b(val);
  emb[(size_t)m * 192 + 96 + cc] = f2b(sgn * val);
}

// corr[h][m] = sum_d (rrb[h,d]-rwb[h,d]) * rk[m, h*64+d]   (biases f32)
__global__ void k_corr(const unsigned short* __restrict__ rk,
                       const float* __restrict__ rwb,
                       const float* __restrict__ rrb,
                       float* __restrict__ corr) {
  int idx = blockIdx.x * 256 + threadIdx.x;  // 8*3072
  if (idx >= 8 * 3072) return;
  int h = idx / 3072, m = idx % 3072;
  float s = 0.f;
  if (m < 3071) {
    for (int d = 0; d < 64; d++)
      s += (rrb[h * 64 + d] - rwb[h * 64 + d]) * b2f(rk[(size_t)m * 512 + h * 64 + d]);
  }
  corr[idx] = s;
}

// ---------------------------------------------------------------- MFMA GEMM
// C = A[M,K] * Bt[N,K]^T, bf16 in, fp32 accum. Output: bf16 to Cb, or f32 to Cf.
__global__ __launch_bounds__(256) void k_gemm_bt(
    const unsigned short* __restrict__ A, const unsigned short* __restrict__ Bt,
    unsigned short* __restrict__ Cb, float* __restrict__ Cf, int M, int N, int K) {
  __shared__ unsigned short As[4096];  // 128 rows x 32 k
  __shared__ unsigned short Bs[4096];
  int tid = threadIdx.x;
  int w = tid >> 6, L = tid & 63, g = L >> 4, c = L & 15;
  int m0 = blockIdx.y << 7, n0 = blockIdx.x << 7;
  int wm = (w >> 1) << 6, wn = (w & 1) << 6;
  f32x4 acc[4][4];
#pragma unroll
  for (int i = 0; i < 4; i++)
#pragma unroll
    for (int j = 0; j < 4; j++) acc[i][j] = (f32x4){0.f, 0.f, 0.f, 0.f};
  int nkt = K >> 5;
  for (int kt = 0; kt < nkt; kt++) {
    int k0 = kt << 5;
    bf16x8 va[2], vb[2];
#pragma unroll
    for (int i2 = 0; i2 < 2; i2++) {
      int cidx = tid + (i2 << 8);
      int row = cidx >> 2, kc = (cidx & 3) << 3;
      int ra = m0 + row;
      if (ra >= M) ra = M - 1;
      va[i2] = *(const bf16x8*)(A + (size_t)ra * K + k0 + kc);
      vb[i2] = *(const bf16x8*)(Bt + (size_t)(n0 + row) * K + k0 + kc);
    }
    __syncthreads();
#pragma unroll
    for (int i2 = 0; i2 < 2; i2++) {
      int cidx = tid + (i2 << 8);
      *(bf16x8*)(As + cidx * 8) = va[i2];
      *(bf16x8*)(Bs + cidx * 8) = vb[i2];
    }
    __syncthreads();
    bf16x8 af[4], bfr[4];
#pragma unroll
    for (int t = 0; t < 4; t++) af[t] = *(const bf16x8*)(As + (wm + t * 16 + c) * 32 + g * 8);
#pragma unroll
    for (int t = 0; t < 4; t++) bfr[t] = *(const bf16x8*)(Bs + (wn + t * 16 + c) * 32 + g * 8);
#pragma unroll
    for (int mt = 0; mt < 4; mt++)
#pragma unroll
      for (int nt = 0; nt < 4; nt++)
        acc[mt][nt] = __builtin_amdgcn_mfma_f32_16x16x32_bf16(af[mt], bfr[nt], acc[mt][nt], 0, 0, 0);
  }
#pragma unroll
  for (int mt = 0; mt < 4; mt++)
#pragma unroll
    for (int nt = 0; nt < 4; nt++)
#pragma unroll
      for (int r = 0; r < 4; r++) {
        int rr = m0 + wm + mt * 16 + g * 4 + r;
        if (rr < M) {
          size_t o = (size_t)rr * N + n0 + wn + nt * 16 + c;
          if (Cf) Cf[o] = acc[mt][nt][r];
          else Cb[o] = f2b(acc[mt][nt][r]);
        }
      }
}

// ------------------------------------------------------------ flash attention
// grid (24, 16): blockIdx.x = q-tile (64 rows), blockIdx.y = b*8+h.
__global__ __launch_bounds__(256) void k_attn(
    const unsigned short* __restrict__ QKV, const unsigned short* __restrict__ rk,
    const unsigned short* __restrict__ Vt, const float* __restrict__ corr,
    const float* __restrict__ rwb, unsigned short* __restrict__ O) {
  __shared__ float Rbuf[4][16][132];           // per-wave rel band [qrow][mlocal]
  __shared__ unsigned short Pbuf[4][16][72];   // per-wave P (A-operand layout)
  const int tid = threadIdx.x;
  const int w = tid >> 6, L = tid & 63, g = L >> 4, c = L & 15;
  const int i0 = blockIdx.x << 6;
  const int bh = blockIdx.y;
  const int b = bh >> 3, h = bh & 7;

  // Q fragment (A-operand): row = w*16 + c, k = ks*32 + g*8 + j. q*K^-0.5 + r_w_bias.
  bf16x8 aq[2];
  {
    const unsigned short* qrow = QKV + (size_t)(b * 1536 + i0 + w * 16 + c) * 2560 + h * 64;
#pragma unroll
    for (int ks = 0; ks < 2; ks++) {
      union { bf16x8 v; unsigned short s[8]; } u;
#pragma unroll
      for (int j = 0; j < 8; j++) {
        int d = ks * 32 + g * 8 + j;
        u.s[j] = f2b(b2f(qrow[d]) * 0.125f + rwb[h * 64 + d]);
      }
      aq[ks] = u.v;
    }
  }

  f32x4 Ofr[12];
#pragma unroll
  for (int t = 0; t < 12; t++) Ofr[t] = (f32x4){0.f, 0.f, 0.f, 0.f};
  float mrow[4], lrow[4];
#pragma unroll
  for (int r = 0; r < 4; r++) { mrow[r] = -1e30f; lrow[r] = 0.f; }

  const size_t kbase = (size_t)(b * 1536) * 2560 + 512 + h * 64;
  const unsigned short* vtb = Vt + (size_t)(bh * 192) * 1536;
  const float* corrh = corr + h * 3072;

  for (int j0 = 0; j0 < 1536; j0 += 64) {
    const int mbase = j0 - i0 + 1472;
    // ---- content scores
    f32x4 Sc[4];
#pragma unroll
    for (int nt = 0; nt < 4; nt++) {
      const unsigned short* krow = QKV + kbase + (size_t)(j0 + nt * 16 + c) * 2560;
      f32x4 z = (f32x4){0.f, 0.f, 0.f, 0.f};
      z = __builtin_amdgcn_mfma_f32_16x16x32_bf16(aq[0], *(const bf16x8*)(krow + g * 8), z, 0, 0, 0);
      z = __builtin_amdgcn_mfma_f32_16x16x32_bf16(aq[1], *(const bf16x8*)(krow + 32 + g * 8), z, 0, 0, 0);
      Sc[nt] = z;
    }
    // ---- rel band: R[qrow][mlocal] = (q*s+rwb).rk[mbase+mlocal] + corr
#pragma unroll
    for (int nt2 = 0; nt2 < 8; nt2++) {
      int mg = mbase + nt2 * 16 + c;  // in [0,3071]; row 3071 zeroed, never read back
      const unsigned short* rrow = rk + (size_t)mg * 512 + h * 64;
      f32x4 z = (f32x4){0.f, 0.f, 0.f, 0.f};
      z = __builtin_amdgcn_mfma_f32_16x16x32_bf16(aq[0], *(const bf16x8*)(rrow + g * 8), z, 0, 0, 0);
      z = __builtin_amdgcn_mfma_f32_16x16x32_bf16(aq[1], *(const bf16x8*)(rrow + 32 + g * 8), z, 0, 0, 0);
      float cv = corrh[mg];
#pragma unroll
      for (int r = 0; r < 4; r++) Rbuf[w][g * 4 + r][nt2 * 16 + c] = z[r] + cv;
    }
    __syncthreads();
    // ---- logits = content + shifted rel; mlocal = jj - qi + 63
    float lg[4][4];
#pragma unroll
    for (int nt = 0; nt < 4; nt++)
#pragma unroll
      for (int r = 0; r < 4; r++) {
        int row = g * 4 + r;
        lg[nt][r] = Sc[nt][r] + Rbuf[w][row][nt * 16 + c - w * 16 - row + 63];
      }
    // ---- online softmax
    float al[4];
#pragma unroll
    for (int r = 0; r < 4; r++) {
      float mx = fmaxf(fmaxf(lg[0][r], lg[1][r]), fmaxf(lg[2][r], lg[3][r]));
      mx = fmaxf(mx, __shfl_xor(mx, 1, 64));
      mx = fmaxf(mx, __shfl_xor(mx, 2, 64));
      mx = fmaxf(mx, __shfl_xor(mx, 4, 64));
      mx = fmaxf(mx, __shfl_xor(mx, 8, 64));
      float mn = fmaxf(mrow[r], mx);
      al[r] = __expf(mrow[r] - mn);
      mrow[r] = mn;
    }
#pragma unroll
    for (int r = 0; r < 4; r++) {
      float s0 = 0.f;
#pragma unroll
      for (int nt = 0; nt < 4; nt++) {
        float p = __expf(lg[nt][r] - mrow[r]);
        lg[nt][r] = p;
        s0 += p;
      }
      s0 += __shfl_xor(s0, 1, 64);
      s0 += __shfl_xor(s0, 2, 64);
      s0 += __shfl_xor(s0, 4, 64);
      s0 += __shfl_xor(s0, 8, 64);
      lrow[r] = lrow[r] * al[r] + s0;
    }
    // ---- write P (bf16, A-operand row-major), rescale O, PV MFMA
#pragma unroll
    for (int nt = 0; nt < 4; nt++)
#pragma unroll
      for (int r = 0; r < 4; r++) Pbuf[w][g * 4 + r][nt * 16 + c] = f2b(lg[nt][r]);
    __syncthreads();
#pragma unroll
    for (int t = 0; t < 12; t++)
#pragma unroll
      for (int r = 0; r < 4; r++) Ofr[t][r] *= al[r];
    bf16x8 ap0 = *(const bf16x8*)(&Pbuf[w][c][g * 8]);
    bf16x8 ap1 = *(const bf16x8*)(&Pbuf[w][c][32 + g * 8]);
#pragma unroll
    for (int nt3 = 0; nt3 < 12; nt3++) {
      const unsigned short* vrow = vtb + (size_t)(nt3 * 16 + c) * 1536 + j0;
      Ofr[nt3] = __builtin_amdgcn_mfma_f32_16x16x32_bf16(ap0, *(const bf16x8*)(vrow + g * 8), Ofr[nt3], 0, 0, 0);
      Ofr[nt3] = __builtin_amdgcn_mfma_f32_16x16x32_bf16(ap1, *(const bf16x8*)(vrow + 32 + g * 8), Ofr[nt3], 0, 0, 0);
    }
  }
  // ---- epilogue
#pragma unroll
  for (int t = 0; t < 12; t++)
#pragma unroll
    for (int r = 0; r < 4; r++) {
      float v = Ofr[t][r] / lrow[r];
      O[(size_t)(b * 1536 + i0 + w * 16 + g * 4 + r) * 1536 + h * 192 + t * 16 + c] = f2b(v);
    }
}

// ------------------------------------------------------------------ launcher
extern "C" void kernel_launch(void* const* d_in, const int* in_sizes, int n_in,
                              void* d_out, int out_size, void* d_ws, size_t ws_size,
                              hipStream_t stream) {
  const float* x    = (const float*)d_in[0];
  const float* Wq   = (const float*)d_in[1];
  const float* Wk   = (const float*)d_in[2];
  const float* Wv   = (const float*)d_in[3];
  const float* Wrk  = (const float*)d_in[4];
  const float* Wemb = (const float*)d_in[5];
  const float* rwb  = (const float*)d_in[6];
  const float* rrb  = (const float*)d_in[7];

  char* ws = (char*)d_ws;
  size_t off = 0;
  auto alloc = [&](size_t bytes) -> void* {
    void* p = ws + off;
    off += (bytes + 255) & ~(size_t)255;
    return p;
  };
  unsigned short* xb    = (unsigned short*)alloc((size_t)3072 * 1536 * 2);
  unsigned short* WqkvT = (unsigned short*)alloc((size_t)2560 * 1536 * 2);
  unsigned short* WembT = (unsigned short*)alloc((size_t)1536 * 1536 * 2);
  unsigned short* WrkT  = (unsigned short*)alloc((size_t)512 * 192 * 2);
  unsigned short* QKV   = (unsigned short*)alloc((size_t)3072 * 2560 * 2);
  unsigned short* Vt    = (unsigned short*)alloc((size_t)2 * 1536 * 1536 * 2);
  unsigned short* emb   = (unsigned short*)alloc((size_t)3072 * 192 * 2);
  unsigned short* rkb   = (unsigned short*)alloc((size_t)3072 * 512 * 2);
  float* corr           = (float*)alloc((size_t)8 * 3072 * 4);
  float* pmax           = (float*)alloc(256);
  unsigned short* Obuf  = (unsigned short*)alloc((size_t)3072 * 1536 * 2);

  hipMemsetAsync(pmax, 0, 4, stream);
  // zero the one never-written rkb row reachable by the rel-band MFMA
  hipMemsetAsync(rkb + (size_t)3071 * 512, 0, 512 * 2, stream);

  // x -> bf16
  k_cvt<<<(3072 * 1536 + 255) / 256, 256, 0, stream>>>(x, xb, 3072 * 1536);

  // weight transposes (f32 -> bf16); WqkvT rows: [0,512)=Wq^T, [512,1024)=Wk^T, [1024,2560)=Wv^T
  k_transpose<float><<<dim3(16, 48), 256, 0, stream>>>(Wq, 512, WqkvT, 1536, 1536, 512);
  k_transpose<float><<<dim3(16, 48), 256, 0, stream>>>(Wk, 512, WqkvT + (size_t)512 * 1536, 1536, 1536, 512);
  k_transpose<float><<<dim3(48, 48), 256, 0, stream>>>(Wv, 1536, WqkvT + (size_t)1024 * 1536, 1536, 1536, 1536);
  k_transpose<float><<<dim3(48, 48), 256, 0, stream>>>(Wemb, 1536, WembT, 1536, 1536, 1536);
  k_transpose<float><<<dim3(16, 6), 256, 0, stream>>>(Wrk, 512, WrkT, 192, 192, 512);

  // positional features
  k_posmax<<<384, 256, 0, stream>>>(pmax);
  k_emb<<<1152, 256, 0, stream>>>(emb, pmax);

  // fused QKV projection: [3072,1536] x [2560,1536]^T  -> bf16
  k_gemm_bt<<<dim3(20, 24), 256, 0, stream>>>(xb, WqkvT, QKV, nullptr, 3072, 2560, 1536);
  // rel keys: [3071,192] x [512,192]^T -> bf16
  k_gemm_bt<<<dim3(4, 24), 256, 0, stream>>>(emb, WrkT, rkb, nullptr, 3071, 512, 192);
  // bias-difference correction
  k_corr<<<96, 256, 0, stream>>>(rkb, rwb, rrb, corr);
  // V transpose per batch (bf16 -> bf16): Vt[(b*8+h)*192+v][time]
  k_transpose<unsigned short><<<dim3(48, 48), 256, 0, stream>>>(QKV + 1024, 2560, Vt, 1536, 1536, 1536);
  k_transpose<unsigned short><<<dim3(48, 48), 256, 0, stream>>>(QKV + (size_t)1536 * 2560 + 1024, 2560,
                                                                Vt + (size_t)1536 * 1536, 1536, 1536, 1536);
  // flash attention with folded relative shift
  k_attn<<<dim3(24, 16), 256, 0, stream>>>(QKV, rkb, Vt, corr, rwb, Obuf);
  // output projection: [3072,1536] x [1536,1536]^T -> f32 d_out
  k_gemm_bt<<<dim3(12, 24), 256, 0, stream>>>(Obuf, WembT, nullptr, (float*)d_out, 3072, 1536, 1536);
}

// Round 5
// 470.169 us; speedup vs baseline: 1.1566x; 1.1566x over previous
//
#include <hip/hip_runtime.h>
#include <stdint.h>

#define DEVI __device__ __forceinline__

typedef short bf16x8 __attribute__((ext_vector_type(8)));
typedef float f32x4 __attribute__((ext_vector_type(4)));

DEVI float b2f(unsigned short u) {
  union { unsigned u32; float f; } x;
  x.u32 = ((unsigned)u) << 16;
  return x.f;
}
DEVI unsigned short f2b(float f) {
  union { float f32; unsigned u32; } x;
  x.f32 = f;
  unsigned u = x.u32;
  return (unsigned short)((u + 0x7FFFu + ((u >> 16) & 1u)) >> 16);
}
DEVI unsigned short to_b(float v) { return f2b(v); }
DEVI unsigned short to_b(unsigned short v) { return v; }

// async global->LDS, 16B per lane. LDS dest must be wave-uniform base + lane*16.
DEVI void gload16(const unsigned short* g, unsigned short* l) {
  __builtin_amdgcn_global_load_lds(
      (const __attribute__((address_space(1))) void*)g,
      (__attribute__((address_space(3))) void*)l, 16, 0, 0);
}

// ------------------------------------------------------------ convert f32->bf16
__global__ void k_cvt(const float* __restrict__ src, unsigned short* __restrict__ dst, int n) {
  int i = blockIdx.x * 256 + threadIdx.x;
  if (i < n) dst[i] = f2b(src[i]);
}

// ---------------------------------------------------------------- transpose
template <typename T>
__global__ void k_transpose(const T* __restrict__ src, int src_ld,
                            unsigned short* __restrict__ dst, int dst_ld,
                            int rows, int cols) {
  __shared__ unsigned short t[32][33];
  int tx = threadIdx.x & 31, ty = threadIdx.x >> 5;
  int r0 = blockIdx.y * 32, c0 = blockIdx.x * 32;
#pragma unroll
  for (int i = 0; i < 4; i++) {
    int r = r0 + ty + i * 8, cc = c0 + tx;
    if (r < rows && cc < cols) t[ty + i * 8][tx] = to_b(src[(size_t)r * src_ld + cc]);
  }
  __syncthreads();
#pragma unroll
  for (int i = 0; i < 4; i++) {
    int dr = c0 + ty + i * 8, dc = r0 + tx;
    if (dr < cols && dc < rows) dst[(size_t)dr * dst_ld + dc] = t[tx][ty + i * 8];
  }
}

// ------------------------------------------------------- positional features
DEVI float gamma_prob(float ap, int i) {
  float mean = 48.f * (float)(i + 1);
  float conc = (mean / 24.f) * (mean / 24.f);
  float rate = mean / 576.f;
  if (ap == 0.f) return 1e-8f;
  float logp = (conc - 1.f) * logf(ap) - rate * ap - (lgammaf(conc) - conc * logf(rate));
  return expf(logp) + 1e-8f;
}

__global__ void k_posmax(float* pmax) {
  int idx = blockIdx.x * 256 + threadIdx.x;  // 3071*32 entries
  float prob = 0.f;
  if (idx < 3071 * 32) {
    int m = idx >> 5, i = idx & 31;
    float ap = fabsf((float)(m - 1535));
    prob = gamma_prob(ap, i);
  }
#pragma unroll
  for (int s = 1; s < 64; s <<= 1) prob = fmaxf(prob, __shfl_xor(prob, s, 64));
  if ((threadIdx.x & 63) == 0) atomicMax((unsigned int*)pmax, __float_as_uint(prob));
}

__global__ void k_emb(unsigned short* __restrict__ emb, const float* __restrict__ pmax) {
  int idx = blockIdx.x * 256 + threadIdx.x;  // 3071*96
  if (idx >= 3071 * 96) return;
  int m = idx / 96, cc = idx % 96;
  float ap = fabsf((float)(m - 1535));
  float val;
  if (cc < 32) {
    float max_range = logf(1536.f) * 1.4426950408889634f;
    float l = 3.f + (float)cc * (max_range - 3.f) / 31.f;
    val = exp2f(-ap * exp2f(-l));
  } else if (cc < 64) {
    int i = cc - 32;
    float width = exp2f((float)(i + 1)) - 1.f;
    val = (width > ap) ? 1.f : 0.f;
  } else {
    val = gamma_prob(ap, cc - 64) / pmax[0];
  }
  float sgn = (m > 1535) ? 1.f : ((m < 1535) ? -1.f : 0.f);
  emb[(size_t)m * 192 + cc] = f2b(val);
  emb[(size_t)m * 192 + 96 + cc] = f2b(sgn * val);
}

// corr[h][m] = sum_d (rrb[h,d]-rwb[h,d]) * rk[m, h*64+d]   (biases f32)
__global__ void k_corr(const unsigned short* __restrict__ rk,
                       const float* __restrict__ rwb,
                       const float* __restrict__ rrb,
                       float* __restrict__ corr) {
  int idx = blockIdx.x * 256 + threadIdx.x;  // 8*3072
  if (idx >= 8 * 3072) return;
  int h = idx / 3072, m = idx % 3072;
  float s = 0.f;
  if (m < 3071) {
    const unsigned short* rr = rk + (size_t)m * 512 + h * 64;
#pragma unroll
    for (int ch = 0; ch < 8; ch++) {
      union { bf16x8 b; unsigned short s8[8]; } u;
      u.b = *(const bf16x8*)(rr + ch * 8);
#pragma unroll
      for (int j = 0; j < 8; j++) {
        int d = ch * 8 + j;
        s += (rrb[h * 64 + d] - rwb[h * 64 + d]) * b2f(u.s8[j]);
      }
    }
  }
  corr[idx] = s;
}

// ---------------------------------------------------------------- MFMA GEMM
// C = A[M,K] * Bt[N,K]^T, bf16 in, fp32 accum. Output: bf16 to Cb, or f32 to Cf.
// m97 pattern: global_load_lds width=16 staging.
__global__ __launch_bounds__(256) void k_gemm_bt(
    const unsigned short* __restrict__ A, const unsigned short* __restrict__ Bt,
    unsigned short* __restrict__ Cb, float* __restrict__ Cf, int M, int N, int K) {
  __shared__ unsigned short As[4096];  // 128 rows x 32 k
  __shared__ unsigned short Bs[4096];
  int tid = threadIdx.x;
  int w = tid >> 6, L = tid & 63, g = L >> 4, c = L & 15;
  int m0 = blockIdx.y << 7, n0 = blockIdx.x << 7;
  int wm = (w >> 1) << 6, wn = (w & 1) << 6;
  f32x4 acc[4][4];
#pragma unroll
  for (int i = 0; i < 4; i++)
#pragma unroll
    for (int j = 0; j < 4; j++) acc[i][j] = (f32x4){0.f, 0.f, 0.f, 0.f};
  int nkt = K >> 5;
  for (int kt = 0; kt < nkt; kt++) {
    int k0 = kt << 5;
#pragma unroll
    for (int i2 = 0; i2 < 2; i2++) {
      int cidx = tid + (i2 << 8);
      int row = cidx >> 2, kc = (cidx & 3) << 3;
      int ra = m0 + row;
      if (ra >= M) ra = M - 1;
      gload16(A + (size_t)ra * K + k0 + kc, As + cidx * 8);
      gload16(Bt + (size_t)(n0 + row) * K + k0 + kc, Bs + cidx * 8);
    }
    __syncthreads();
    bf16x8 af[4], bfr[4];
#pragma unroll
    for (int t = 0; t < 4; t++) af[t] = *(const bf16x8*)(As + (wm + t * 16 + c) * 32 + g * 8);
#pragma unroll
    for (int t = 0; t < 4; t++) bfr[t] = *(const bf16x8*)(Bs + (wn + t * 16 + c) * 32 + g * 8);
#pragma unroll
    for (int mt = 0; mt < 4; mt++)
#pragma unroll
      for (int nt = 0; nt < 4; nt++)
        acc[mt][nt] = __builtin_amdgcn_mfma_f32_16x16x32_bf16(af[mt], bfr[nt], acc[mt][nt], 0, 0, 0);
    __syncthreads();
  }
#pragma unroll
  for (int mt = 0; mt < 4; mt++)
#pragma unroll
    for (int nt = 0; nt < 4; nt++)
#pragma unroll
      for (int r = 0; r < 4; r++) {
        int rr = m0 + wm + mt * 16 + g * 4 + r;
        if (rr < M) {
          size_t o = (size_t)rr * N + n0 + wn + nt * 16 + c;
          if (Cf) Cf[o] = acc[mt][nt][r];
          else Cb[o] = f2b(acc[mt][nt][r]);
        }
      }
}

// ------------------------------------------------------------ flash attention
// grid (96, 16): blockIdx.x = 16-row q-tile, blockIdx.y = b*8+h.
// All 4 waves share the same 16 q-rows; wave w handles key quarter
// [w*384, (w+1)*384). Partial (m,l,O) merged via 2-stage LDS tree.
__global__ __launch_bounds__(256, 4) void k_attn(
    const unsigned short* __restrict__ QKV, const unsigned short* __restrict__ rk,
    const unsigned short* __restrict__ Vt, const float* __restrict__ corr,
    const float* __restrict__ rwb, unsigned short* __restrict__ O) {
  __shared__ float smem[7424];  // loop: Rbuf 5120 f + Pbuf 2304 f; combine: 6800 f
  float (*Rbuf)[16][80] = (float (*)[16][80])smem;          // per-wave rel band, t-48
  unsigned short (*Pbuf)[16][72] = (unsigned short (*)[16][72])(smem + 5120);
  const int tid = threadIdx.x;
  const int w = tid >> 6, L = tid & 63, g = L >> 4, c = L & 15;
  const int i0 = blockIdx.x << 4;     // q-tile base (16 rows)
  const int bh = blockIdx.y;
  const int b = bh >> 3, h = bh & 7;

  // Q fragment (A-operand): row = c, k = ks*32 + g*8 + j. q*K^-0.5 + r_w_bias.
  bf16x8 aq[2];
  {
    const unsigned short* qrow = QKV + (size_t)(b * 1536 + i0 + c) * 2560 + h * 64;
#pragma unroll
    for (int ks = 0; ks < 2; ks++) {
      union { bf16x8 v; unsigned short s[8]; } u;
#pragma unroll
      for (int j = 0; j < 8; j++) {
        int d = ks * 32 + g * 8 + j;
        u.s[j] = f2b(b2f(qrow[d]) * 0.125f + rwb[h * 64 + d]);
      }
      aq[ks] = u.v;
    }
  }

  f32x4 Ofr[12];
#pragma unroll
  for (int t = 0; t < 12; t++) Ofr[t] = (f32x4){0.f, 0.f, 0.f, 0.f};
  float mrow[4], lrow[4];
#pragma unroll
  for (int r = 0; r < 4; r++) { mrow[r] = -1e30f; lrow[r] = 0.f; }

  const size_t kbase = (size_t)(b * 1536) * 2560 + 512 + h * 64;
  const unsigned short* vtb = Vt + (size_t)(bh * 192) * 1536;
  const float* corrh = corr + h * 3072;

  for (int jt = 0; jt < 6; jt++) {
    const int j0 = w * 384 + jt * 64;
    const int moff = j0 - i0 + 1520;  // >= 0; m for band t=48
    // ---- content scores
    f32x4 Sc[4];
#pragma unroll
    for (int nt = 0; nt < 4; nt++) {
      const unsigned short* krow = QKV + kbase + (size_t)(j0 + nt * 16 + c) * 2560;
      f32x4 z = (f32x4){0.f, 0.f, 0.f, 0.f};
      z = __builtin_amdgcn_mfma_f32_16x16x32_bf16(aq[0], *(const bf16x8*)(krow + g * 8), z, 0, 0, 0);
      z = __builtin_amdgcn_mfma_f32_16x16x32_bf16(aq[1], *(const bf16x8*)(krow + 32 + g * 8), z, 0, 0, 0);
      Sc[nt] = z;
    }
    // ---- rel band over t in [48,128): R[qr][t-48] = A(q).rk[moff + t-48] + corr
#pragma unroll
    for (int nt2 = 0; nt2 < 5; nt2++) {
      int mg = moff + nt2 * 16 + c;  // in [0, 3071]; row 3071 zeroed, never read
      const unsigned short* rrow = rk + (size_t)mg * 512 + h * 64;
      f32x4 z = (f32x4){0.f, 0.f, 0.f, 0.f};
      z = __builtin_amdgcn_mfma_f32_16x16x32_bf16(aq[0], *(const bf16x8*)(rrow + g * 8), z, 0, 0, 0);
      z = __builtin_amdgcn_mfma_f32_16x16x32_bf16(aq[1], *(const bf16x8*)(rrow + 32 + g * 8), z, 0, 0, 0);
      float cv = corrh[mg];
#pragma unroll
      for (int r = 0; r < 4; r++) Rbuf[w][g * 4 + r][nt2 * 16 + c] = z[r] + cv;
    }
    __syncthreads();
    // ---- logits = content + shifted rel; stored t-48 = jj - qr + 15
    float lg[4][4];
#pragma unroll
    for (int nt = 0; nt < 4; nt++)
#pragma unroll
      for (int r = 0; r < 4; r++) {
        int row = g * 4 + r;
        lg[nt][r] = Sc[nt][r] + Rbuf[w][row][nt * 16 + c - row + 15];
      }
    // ---- online softmax (rows = g*4+r, reduce over 16 c-lanes)
    float al[4];
#pragma unroll
    for (int r = 0; r < 4; r++) {
      float mx = fmaxf(fmaxf(lg[0][r], lg[1][r]), fmaxf(lg[2][r], lg[3][r]));
      mx = fmaxf(mx, __shfl_xor(mx, 1, 64));
      mx = fmaxf(mx, __shfl_xor(mx, 2, 64));
      mx = fmaxf(mx, __shfl_xor(mx, 4, 64));
      mx = fmaxf(mx, __shfl_xor(mx, 8, 64));
      float mn = fmaxf(mrow[r], mx);
      al[r] = __expf(mrow[r] - mn);
      mrow[r] = mn;
    }
#pragma unroll
    for (int r = 0; r < 4; r++) {
      float s0 = 0.f;
#pragma unroll
      for (int nt = 0; nt < 4; nt++) {
        float p = __expf(lg[nt][r] - mrow[r]);
        lg[nt][r] = p;
        s0 += p;
      }
      s0 += __shfl_xor(s0, 1, 64);
      s0 += __shfl_xor(s0, 2, 64);
      s0 += __shfl_xor(s0, 4, 64);
      s0 += __shfl_xor(s0, 8, 64);
      lrow[r] = lrow[r] * al[r] + s0;
    }
    // ---- write P (bf16, A-operand row-major), rescale O, PV MFMA
#pragma unroll
    for (int nt = 0; nt < 4; nt++)
#pragma unroll
      for (int r = 0; r < 4; r++) Pbuf[w][g * 4 + r][nt * 16 + c] = f2b(lg[nt][r]);
    __syncthreads();
#pragma unroll
    for (int t = 0; t < 12; t++)
#pragma unroll
      for (int r = 0; r < 4; r++) Ofr[t][r] *= al[r];
    bf16x8 ap0 = *(const bf16x8*)(&Pbuf[w][c][g * 8]);
    bf16x8 ap1 = *(const bf16x8*)(&Pbuf[w][c][32 + g * 8]);
#pragma unroll
    for (int nt3 = 0; nt3 < 12; nt3++) {
      const unsigned short* vrow = vtb + (size_t)(nt3 * 16 + c) * 1536 + j0;
      Ofr[nt3] = __builtin_amdgcn_mfma_f32_16x16x32_bf16(ap0, *(const bf16x8*)(vrow + g * 8), Ofr[nt3], 0, 0, 0);
      Ofr[nt3] = __builtin_amdgcn_mfma_f32_16x16x32_bf16(ap1, *(const bf16x8*)(vrow + 32 + g * 8), Ofr[nt3], 0, 0, 0);
    }
  }
  // ---- 2-stage cross-wave merge of (m, l, O) partials
  float* cb = smem;  // reuse; per-slot 3400 floats: O 64x52, m @3328, l @3344
  __syncthreads();
  if (w >= 2) {  // stage 1 publish: waves 2,3 -> slots 0,1
    float* base = cb + (w - 2) * 3400;
#pragma unroll
    for (int t = 0; t < 12; t++) *(f32x4*)(base + L * 52 + t * 4) = Ofr[t];
    if (c == 0)
#pragma unroll
      for (int r = 0; r < 4; r++) {
        base[3328 + g * 4 + r] = mrow[r];
        base[3344 + g * 4 + r] = lrow[r];
      }
  }
  __syncthreads();
  if (w < 2) {  // stage 1 merge
    float* base = cb + w * 3400;
    float a1[4], a2[4];
#pragma unroll
    for (int r = 0; r < 4; r++) {
      int row = g * 4 + r;
      float m2 = base[3328 + row], l2 = base[3344 + row];
      float mn = fmaxf(mrow[r], m2);
      a1[r] = __expf(mrow[r] - mn);
      a2[r] = __expf(m2 - mn);
      lrow[r] = lrow[r] * a1[r] + l2 * a2[r];
      mrow[r] = mn;
    }
#pragma unroll
    for (int t = 0; t < 12; t++) {
      f32x4 o2 = *(const f32x4*)(base + L * 52 + t * 4);
#pragma unroll
      for (int r = 0; r < 4; r++) Ofr[t][r] = Ofr[t][r] * a1[r] + o2[r] * a2[r];
    }
  }
  __syncthreads();
  if (w == 1) {  // stage 2 publish
    float* base = cb;
#pragma unroll
    for (int t = 0; t < 12; t++) *(f32x4*)(base + L * 52 + t * 4) = Ofr[t];
    if (c == 0)
#pragma unroll
      for (int r = 0; r < 4; r++) {
        base[3328 + g * 4 + r] = mrow[r];
        base[3344 + g * 4 + r] = lrow[r];
      }
  }
  __syncthreads();
  if (w == 0) {  // stage 2 merge + store
    float* base = cb;
    float a1[4], a2[4];
#pragma unroll
    for (int r = 0; r < 4; r++) {
      int row = g * 4 + r;
      float m2 = base[3328 + row], l2 = base[3344 + row];
      float mn = fmaxf(mrow[r], m2);
      a1[r] = __expf(mrow[r] - mn);
      a2[r] = __expf(m2 - mn);
      lrow[r] = lrow[r] * a1[r] + l2 * a2[r];
      mrow[r] = mn;
    }
#pragma unroll
    for (int t = 0; t < 12; t++) {
      f32x4 o2 = *(const f32x4*)(base + L * 52 + t * 4);
#pragma unroll
      for (int r = 0; r < 4; r++) {
        float v = (Ofr[t][r] * a1[r] + o2[r] * a2[r]) / lrow[r];
        O[(size_t)(b * 1536 + i0 + g * 4 + r) * 1536 + h * 192 + t * 16 + c] = f2b(v);
      }
    }
  }
}

// ------------------------------------------------------------------ launcher
extern "C" void kernel_launch(void* const* d_in, const int* in_sizes, int n_in,
                              void* d_out, int out_size, void* d_ws, size_t ws_size,
                              hipStream_t stream) {
  const float* x    = (const float*)d_in[0];
  const float* Wq   = (const float*)d_in[1];
  const float* Wk   = (const float*)d_in[2];
  const float* Wv   = (const float*)d_in[3];
  const float* Wrk  = (const float*)d_in[4];
  const float* Wemb = (const float*)d_in[5];
  const float* rwb  = (const float*)d_in[6];
  const float* rrb  = (const float*)d_in[7];

  char* ws = (char*)d_ws;
  size_t off = 0;
  auto alloc = [&](size_t bytes) -> void* {
    void* p = ws + off;
    off += (bytes + 255) & ~(size_t)255;
    return p;
  };
  unsigned short* xb    = (unsigned short*)alloc((size_t)3072 * 1536 * 2);
  unsigned short* WqkvT = (unsigned short*)alloc((size_t)2560 * 1536 * 2);
  unsigned short* WembT = (unsigned short*)alloc((size_t)1536 * 1536 * 2);
  unsigned short* WrkT  = (unsigned short*)alloc((size_t)512 * 192 * 2);
  unsigned short* QKV   = (unsigned short*)alloc((size_t)3072 * 2560 * 2);
  unsigned short* Vt    = (unsigned short*)alloc((size_t)2 * 1536 * 1536 * 2);
  unsigned short* emb   = (unsigned short*)alloc((size_t)3072 * 192 * 2);
  unsigned short* rkb   = (unsigned short*)alloc((size_t)3072 * 512 * 2);
  float* corr           = (float*)alloc((size_t)8 * 3072 * 4);
  float* pmax           = (float*)alloc(256);
  unsigned short* Obuf  = (unsigned short*)alloc((size_t)3072 * 1536 * 2);

  hipMemsetAsync(pmax, 0, 4, stream);
  // zero the one never-written rkb row reachable by the rel-band MFMA
  hipMemsetAsync(rkb + (size_t)3071 * 512, 0, 512 * 2, stream);

  // x -> bf16
  k_cvt<<<(3072 * 1536 + 255) / 256, 256, 0, stream>>>(x, xb, 3072 * 1536);

  // weight transposes (f32 -> bf16); WqkvT rows: [0,512)=Wq^T, [512,1024)=Wk^T, [1024,2560)=Wv^T
  k_transpose<float><<<dim3(16, 48), 256, 0, stream>>>(Wq, 512, WqkvT, 1536, 1536, 512);
  k_transpose<float><<<dim3(16, 48), 256, 0, stream>>>(Wk, 512, WqkvT + (size_t)512 * 1536, 1536, 1536, 512);
  k_transpose<float><<<dim3(48, 48), 256, 0, stream>>>(Wv, 1536, WqkvT + (size_t)1024 * 1536, 1536, 1536, 1536);
  k_transpose<float><<<dim3(48, 48), 256, 0, stream>>>(Wemb, 1536, WembT, 1536, 1536, 1536);
  k_transpose<float><<<dim3(16, 6), 256, 0, stream>>>(Wrk, 512, WrkT, 192, 192, 512);

  // positional features
  k_posmax<<<384, 256, 0, stream>>>(pmax);
  k_emb<<<1152, 256, 0, stream>>>(emb, pmax);

  // fused QKV projection: [3072,1536] x [2560,1536]^T  -> bf16
  k_gemm_bt<<<dim3(20, 24), 256, 0, stream>>>(xb, WqkvT, QKV, nullptr, 3072, 2560, 1536);
  // rel keys: [3071,192] x [512,192]^T -> bf16
  k_gemm_bt<<<dim3(4, 24), 256, 0, stream>>>(emb, WrkT, rkb, nullptr, 3071, 512, 192);
  // bias-difference correction
  k_corr<<<96, 256, 0, stream>>>(rkb, rwb, rrb, corr);
  // V transpose per batch (bf16 -> bf16): Vt[(b*8+h)*192+v][time]
  k_transpose<unsigned short><<<dim3(48, 48), 256, 0, stream>>>(QKV + 1024, 2560, Vt, 1536, 1536, 1536);
  k_transpose<unsigned short><<<dim3(48, 48), 256, 0, stream>>>(QKV + (size_t)1536 * 2560 + 1024, 2560,
                                                                Vt + (size_t)1536 * 1536, 1536, 1536, 1536);
  // flash attention, 4-way key split per 16-row q-tile
  k_attn<<<dim3(96, 16), 256, 0, stream>>>(QKV, rkb, Vt, corr, rwb, Obuf);
  // output projection: [3072,1536] x [1536,1536]^T -> f32 d_out
  k_gemm_bt<<<dim3(12, 24), 256, 0, stream>>>(Obuf, WembT, nullptr, (float*)d_out, 3072, 1536, 1536);
}